// Round 8
// baseline (51.951 us; speedup 1.0000x reference)
//
#include <hip/hip_runtime.h>
#include <hip/hip_bf16.h>

// ConvexReLUCNN: B=512, C=3, H=W=64, KERNEL=3
//   K=27, L=62*62=3844, M=512, O=10
#define ODIM   10
#define HOg    62
#define LDIM   3844
#define CHW    12288
#define BATCH  512
#define KO     270
#define KOP    272        // ko padded to 17*16
#define MDIM   512        // reduction dim (neurons)
#define GTN    3904       // n padded to 61*64 for Gt

typedef __attribute__((ext_vector_type(8))) short bfrag;   // 8 bf16 (4 VGPR)
typedef __attribute__((ext_vector_type(4))) float f32x4;

// ---------------------------------------------------------------------------
// K0a: Pdt[ko][m] (bf16) = v[m][ko] - w[m][ko]; rows 270..271 zero.
// ---------------------------------------------------------------------------
__global__ __launch_bounds__(256)
void pdt_kernel(const float* __restrict__ v, const float* __restrict__ w,
                __hip_bfloat16* __restrict__ Pdt) {
    int idx = blockIdx.x * 256 + threadIdx.x;      // m*KOP + ko
    if (idx >= MDIM * KOP) return;
    int m  = idx / KOP;
    int ko = idx - m * KOP;
    float val = (ko < KO) ? (v[m * KO + ko] - w[m * KO + ko]) : 0.f;
    Pdt[(size_t)ko * MDIM + m] = __float2bfloat16(val);
}

// ---------------------------------------------------------------------------
// K0b: Gt[n][m] (bf16) = G[m][n]; rows n>=3844 zero. LDS-tiled 64x64 transpose.
// ---------------------------------------------------------------------------
__global__ __launch_bounds__(256)
void gt_kernel(const float* __restrict__ G, __hip_bfloat16* __restrict__ Gt) {
    __shared__ float tile[64][65];
    const int n0 = blockIdx.x * 64;    // 0..60 -> up to 3903
    const int m0 = blockIdx.y * 64;    // 0..7  -> up to 511
    const int tc = threadIdx.x & 63;   // n within tile (coalesced read)
    const int tr = threadIdx.x >> 6;   // 0..3

#pragma unroll
    for (int rr = 0; rr < 64; rr += 4) {
        int n = n0 + tc;
        tile[rr + tr][tc] = (n < LDIM) ? G[(size_t)(m0 + rr + tr) * LDIM + n] : 0.f;
    }
    __syncthreads();

    const int nr = threadIdx.x >> 2;          // n-row within tile
    const int ms = (threadIdx.x & 3) * 16;    // m-segment
    __hip_bfloat16 buf[16];
#pragma unroll
    for (int i = 0; i < 16; ++i)
        buf[i] = __float2bfloat16(tile[ms + i][nr]);
    __hip_bfloat16* dst = Gt + (size_t)(n0 + nr) * MDIM + m0 + ms;
    *reinterpret_cast<uint4*>(dst)     = *reinterpret_cast<uint4*>(&buf[0]);
    *reinterpret_cast<uint4*>(dst + 8) = *reinterpret_cast<uint4*>(&buf[8]);
}

// ---------------------------------------------------------------------------
// K1: T[ko][n] (fp32) = sum_m Pdt[ko][m] * Gt[n][m]   (gemm_bt pattern)
// mfma_f32_16x16x32_bf16; wave = 16ko x 64n, K=512 in 16 steps.
// Block = 4 waves (4 n-tiles); grid 272 = 8 xcd x 2 st-hi x 17 ko-tiles,
// mapped so blocks sharing a Gt panel (same n-supertile) share an XCD.
// Frag layout (m97-verified): A/B lane row = lane&15, k-off = (lane>>4)*8;
// C/D: col = lane&15, row = (lane>>4)*4 + reg.
// ---------------------------------------------------------------------------
__global__ __launch_bounds__(256)
void tmfma_kernel(const __hip_bfloat16* __restrict__ Pdt,
                  const __hip_bfloat16* __restrict__ Gt,
                  float* __restrict__ T) {
    const int bid   = blockIdx.x;
    const int xcd   = bid & 7;
    const int inner = bid >> 3;        // 0..33
    const int sthi  = inner & 1;
    const int kt    = inner >> 1;      // ko-tile 0..16
    const int st    = xcd + 8 * sthi;  // n-supertile 0..15

    const int wv   = threadIdx.x >> 6;
    const int lane = threadIdx.x & 63;
    const int tile = st * 4 + wv;      // n-tile of 64
    if (tile >= 61) return;            // wave-level exit; no barriers below

    const int n0  = tile * 64;
    const int ko0 = kt * 16;
    const int row = lane & 15;
    const int kg  = lane >> 4;         // 0..3

    const __hip_bfloat16* Ap = Pdt + (size_t)(ko0 + row) * MDIM + kg * 8;
    const __hip_bfloat16* Bp = Gt  + (size_t)(n0 + row) * MDIM + kg * 8;

    f32x4 acc[4];
#pragma unroll
    for (int j = 0; j < 4; ++j) acc[j] = (f32x4){0.f, 0.f, 0.f, 0.f};

#pragma unroll 2
    for (int ks = 0; ks < 16; ++ks) {
        bfrag a = *reinterpret_cast<const bfrag*>(Ap + ks * 32);
#pragma unroll
        for (int j = 0; j < 4; ++j) {
            bfrag b = *reinterpret_cast<const bfrag*>(Bp + (size_t)j * 16 * MDIM + ks * 32);
            acc[j] = __builtin_amdgcn_mfma_f32_16x16x32_bf16(a, b, acc[j], 0, 0, 0);
        }
    }

#pragma unroll
    for (int j = 0; j < 4; ++j) {
        int col = n0 + j * 16 + row;
        if (col < LDIM) {
#pragma unroll
            for (int r = 0; r < 4; ++r) {
                int ro = ko0 + kg * 4 + r;
                if (ro < KO)
                    T[(size_t)ro * LDIM + col] = acc[j][r];
            }
        }
    }
}

// ---------------------------------------------------------------------------
// K2: fold T (ko, pix) -> S[o][c*4096 + h*64 + w] (fp32, single partial)
// ---------------------------------------------------------------------------
__global__ __launch_bounds__(256)
void fold_kernel(const float* __restrict__ T, float* __restrict__ S) {
    int idx = blockIdx.x * 256 + threadIdx.x;   // o*CHW + chw
    if (idx >= ODIM * CHW) return;
    int o   = idx / CHW;
    int chw = idx - o * CHW;
    int c = chw >> 12;
    int h = (chw >> 6) & 63;
    int w = chw & 63;

    float s = 0.f;
    for (int i = 0; i < 3; ++i) {
        int pi = h - i;
        if ((unsigned)pi >= HOg) continue;
        for (int j = 0; j < 3; ++j) {
            int pj = w - j;
            if ((unsigned)pj >= HOg) continue;
            int ko = (c * 9 + i * 3 + j) * ODIM + o;
            s += T[(size_t)ko * LDIM + pi * HOg + pj];
        }
    }
    S[idx] = s;
}

// ---------------------------------------------------------------------------
// K3: out[b][o] = sum_chw x[b][chw] * S[o][chw]; 2 images/block, 256 blocks.
// ---------------------------------------------------------------------------
__global__ __launch_bounds__(256)
void out_gemm_kernel(const float* __restrict__ X,
                     const float* __restrict__ S,
                     float* __restrict__ out) {
    const int b0  = blockIdx.x * 2;
    const int tid = threadIdx.x;
    const int NV  = CHW / 4;   // 3072
    const float4* X0 = reinterpret_cast<const float4*>(X) + (size_t)b0 * NV;
    const float4* X1 = X0 + NV;
    const float4* S4 = reinterpret_cast<const float4*>(S);

    float acc0[ODIM], acc1[ODIM];
#pragma unroll
    for (int o = 0; o < ODIM; ++o) { acc0[o] = 0.f; acc1[o] = 0.f; }

    for (int i = tid; i < NV; i += 256) {
        float4 a = X0[i];
        float4 b = X1[i];
#pragma unroll
        for (int o = 0; o < ODIM; ++o) {
            float4 sv = S4[(size_t)o * NV + i];
            acc0[o] += a.x * sv.x + a.y * sv.y + a.z * sv.z + a.w * sv.w;
            acc1[o] += b.x * sv.x + b.y * sv.y + b.z * sv.z + b.w * sv.w;
        }
    }

#pragma unroll
    for (int o = 0; o < ODIM; ++o) {
        float s0 = acc0[o], s1 = acc1[o];
        for (int off = 32; off > 0; off >>= 1) {
            s0 += __shfl_down(s0, off, 64);
            s1 += __shfl_down(s1, off, 64);
        }
        acc0[o] = s0; acc1[o] = s1;
    }

    __shared__ float red[4][2 * ODIM];
    int wave = tid >> 6;
    int lane = tid & 63;
    if (lane == 0) {
#pragma unroll
        for (int o = 0; o < ODIM; ++o) {
            red[wave][o] = acc0[o];
            red[wave][ODIM + o] = acc1[o];
        }
    }
    __syncthreads();
    if (tid < 2 * ODIM) {
        float tsum = red[0][tid] + red[1][tid] + red[2][tid] + red[3][tid];
        int bt = tid / ODIM;
        int o  = tid - bt * ODIM;
        out[(size_t)(b0 + bt) * ODIM + o] = tsum;
    }
}

extern "C" void kernel_launch(void* const* d_in, const int* in_sizes, int n_in,
                              void* d_out, int out_size, void* d_ws, size_t ws_size,
                              hipStream_t stream) {
    const float* x = (const float*)d_in[0];   // (512, 3, 64, 64)
    const float* G = (const float*)d_in[1];   // (512, 3844)
    const float* v = (const float*)d_in[2];   // (512, 27, 10)
    const float* w = (const float*)d_in[3];   // (512, 27, 10)
    float* out = (float*)d_out;               // (512, 10)

    // ws layout (16B-aligned offsets):
    //   T   fp32 [270][3844]  = 4,151,520 B
    //   Gt  bf16 [3904][512]  = 3,997,696 B
    //   Pdt bf16 [272][512]   =   278,528 B
    //   S   fp32 [10][12288]  =   491,520 B
    char* wsb = (char*)d_ws;
    float*          T   = (float*)wsb;
    __hip_bfloat16* Gt  = (__hip_bfloat16*)(wsb + 4151520);
    __hip_bfloat16* Pdt = (__hip_bfloat16*)(wsb + 4151520 + 3997696);
    float*          S   = (float*)(wsb + 4151520 + 3997696 + 278528);

    pdt_kernel<<<(MDIM * KOP + 255) / 256, 256, 0, stream>>>(v, w, Pdt);

    gt_kernel<<<dim3(61, 8), 256, 0, stream>>>(G, Gt);

    tmfma_kernel<<<272, 256, 0, stream>>>(Pdt, Gt, T);

    fold_kernel<<<(ODIM * CHW + 255) / 256, 256, 0, stream>>>(T, S);

    out_gemm_kernel<<<BATCH / 2, 256, 0, stream>>>(x, S, out);
}

// Round 9
// 51.441 us; speedup vs baseline: 1.0099x; 1.0099x over previous
//
#include <hip/hip_runtime.h>
#include <hip/hip_bf16.h>

// ConvexReLUCNN: B=512, C=3, H=W=64, KERNEL=3
//   K=27, L=62*62=3844, M=512, O=10
#define ODIM   10
#define HOg    62
#define LDIM   3844
#define CHW    12288
#define BATCH  512
#define KO     270
#define KOP    272        // ko padded to 17*16
#define MDIM   512        // reduction dim (neurons)

typedef __attribute__((ext_vector_type(8))) short bfrag;   // 8 bf16 (4 VGPR)
typedef __attribute__((ext_vector_type(4))) float f32x4;

// ---------------------------------------------------------------------------
// K0 (fused prep), block-partitioned grid of 1512:
//   blocks [0,488):    Gt[n][m] (bf16) = G[m][n], 64x64 LDS-tiled transpose
//   blocks [488,1032):  Pdt[ko][m] (bf16) = v[m][ko]-w[m][ko] (ko>=270 -> 0)
//   blocks [1032,1512): S = 0  (accumulated by atomics in K1)
// ---------------------------------------------------------------------------
__global__ __launch_bounds__(256)
void prep_kernel(const float* __restrict__ G,
                 const float* __restrict__ v, const float* __restrict__ w,
                 __hip_bfloat16* __restrict__ Gt,
                 __hip_bfloat16* __restrict__ Pdt,
                 float* __restrict__ S) {
    const int b = blockIdx.x;
    if (b < 488) {
        // --- Gt transpose tile ---
        __shared__ float tile[64][65];
        const int nTile = b % 61;
        const int mTile = b / 61;          // 0..7
        const int n0 = nTile * 64;
        const int m0 = mTile * 64;
        const int tc = threadIdx.x & 63;
        const int tr = threadIdx.x >> 6;
#pragma unroll
        for (int rr = 0; rr < 64; rr += 4) {
            int n = n0 + tc;
            tile[rr + tr][tc] = (n < LDIM) ? G[(size_t)(m0 + rr + tr) * LDIM + n] : 0.f;
        }
        __syncthreads();
        const int nr = threadIdx.x >> 2;          // n-row within tile
        const int ms = (threadIdx.x & 3) * 16;    // m-segment
        __hip_bfloat16 buf[16];
#pragma unroll
        for (int i = 0; i < 16; ++i)
            buf[i] = __float2bfloat16(tile[ms + i][nr]);
        __hip_bfloat16* dst = Gt + (size_t)(n0 + nr) * MDIM + m0 + ms;
        *reinterpret_cast<uint4*>(dst)     = *reinterpret_cast<uint4*>(&buf[0]);
        *reinterpret_cast<uint4*>(dst + 8) = *reinterpret_cast<uint4*>(&buf[8]);
    } else if (b < 1032) {
        // --- Pdt ---
        int idx = (b - 488) * 256 + threadIdx.x;   // m*KOP + ko, 544*256 exact
        int m  = idx / KOP;
        int ko = idx - m * KOP;
        float val = (ko < KO) ? (v[m * KO + ko] - w[m * KO + ko]) : 0.f;
        Pdt[(size_t)ko * MDIM + m] = __float2bfloat16(val);
    } else {
        // --- S zero ---
        int idx = (b - 1032) * 256 + threadIdx.x;  // 480*256 = 122880 exact
        S[idx] = 0.f;
    }
}

// ---------------------------------------------------------------------------
// K1: for each (ko, n): t = sum_m Pdt[ko][m]*Gt[n][m]  (mfma 16x16x32 bf16,
// m97-verified fragment mapping, proven correct in round 8), then scatter
//   S[o, c, pi+i, pj+jk] += t   where ko=(c*9+i*3+jk)*10+o, n=pi*62+pj
// (each (ko,n) maps to exactly ONE S element -> fold kernel eliminated).
// Grid 272 = 8 xcd x 2 sthi x 17 kt; blocks sharing a Gt panel share an XCD.
// All 16 A-frags preloaded (ILP); B-frag loads pipelined by unroll.
// ---------------------------------------------------------------------------
__global__ __launch_bounds__(256)
void tmfma_kernel(const __hip_bfloat16* __restrict__ Pdt,
                  const __hip_bfloat16* __restrict__ Gt,
                  float* __restrict__ S) {
    const int bid   = blockIdx.x;
    const int xcd   = bid & 7;
    const int inner = bid >> 3;        // 0..33
    const int sthi  = inner & 1;
    const int kt    = inner >> 1;      // ko-tile 0..16
    const int st    = xcd + 8 * sthi;  // n-supertile 0..15

    const int wv   = threadIdx.x >> 6;
    const int lane = threadIdx.x & 63;
    const int tile = st * 4 + wv;      // n-tile of 64
    if (tile >= 61) return;            // wave-level exit; no barriers below

    const int n0  = tile * 64;
    const int ko0 = kt * 16;
    const int row = lane & 15;
    const int kg  = lane >> 4;         // 0..3

    const __hip_bfloat16* Ap = Pdt + (size_t)(ko0 + row) * MDIM + kg * 8;
    const __hip_bfloat16* Bp = Gt  + (size_t)(n0 + row) * MDIM + kg * 8;

    // preload all A fragments (64 VGPR) so the K loop is pure B-load + MFMA
    bfrag a[16];
#pragma unroll
    for (int ks = 0; ks < 16; ++ks)
        a[ks] = *reinterpret_cast<const bfrag*>(Ap + ks * 32);

    f32x4 acc[4];
#pragma unroll
    for (int j = 0; j < 4; ++j) acc[j] = (f32x4){0.f, 0.f, 0.f, 0.f};

#pragma unroll 4
    for (int ks = 0; ks < 16; ++ks) {
#pragma unroll
        for (int j = 0; j < 4; ++j) {
            bfrag bfr = *reinterpret_cast<const bfrag*>(Bp + (size_t)j * 16 * MDIM + ks * 32);
            acc[j] = __builtin_amdgcn_mfma_f32_16x16x32_bf16(a[ks], bfr, acc[j], 0, 0, 0);
        }
    }

    // scatter-add into S: per r, decompose ko; per j, decompose n.
    int sbase[4];
    bool kval[4];
#pragma unroll
    for (int r = 0; r < 4; ++r) {
        int ko = ko0 + kg * 4 + r;
        kval[r] = (ko < KO);
        int kc  = kval[r] ? ko : 0;
        int o   = kc % ODIM;
        int rem = kc / ODIM;          // 0..26
        int c   = rem / 9;
        int ij  = rem - c * 9;
        int i   = ij / 3;
        int jk  = ij - i * 3;
        sbase[r] = o * CHW + c * 4096 + i * 64 + jk;
    }
#pragma unroll
    for (int j = 0; j < 4; ++j) {
        int col = n0 + j * 16 + row;
        if (col < LDIM) {
            int pi  = col / HOg;
            int pj  = col - pi * HOg;
            int off = pi * 64 + pj;
#pragma unroll
            for (int r = 0; r < 4; ++r) {
                if (kval[r])
                    atomicAdd(&S[sbase[r] + off], acc[j][r]);
            }
        }
    }
}

// ---------------------------------------------------------------------------
// K2: out[b][o] = sum_chw x[b][chw] * S[o][chw]; 2 images/block, 256 blocks.
// ---------------------------------------------------------------------------
__global__ __launch_bounds__(256)
void out_gemm_kernel(const float* __restrict__ X,
                     const float* __restrict__ S,
                     float* __restrict__ out) {
    const int b0  = blockIdx.x * 2;
    const int tid = threadIdx.x;
    const int NV  = CHW / 4;   // 3072
    const float4* X0 = reinterpret_cast<const float4*>(X) + (size_t)b0 * NV;
    const float4* X1 = X0 + NV;
    const float4* S4 = reinterpret_cast<const float4*>(S);

    float acc0[ODIM], acc1[ODIM];
#pragma unroll
    for (int o = 0; o < ODIM; ++o) { acc0[o] = 0.f; acc1[o] = 0.f; }

    for (int i = tid; i < NV; i += 256) {
        float4 a = X0[i];
        float4 b = X1[i];
#pragma unroll
        for (int o = 0; o < ODIM; ++o) {
            float4 sv = S4[(size_t)o * NV + i];
            acc0[o] += a.x * sv.x + a.y * sv.y + a.z * sv.z + a.w * sv.w;
            acc1[o] += b.x * sv.x + b.y * sv.y + b.z * sv.z + b.w * sv.w;
        }
    }

#pragma unroll
    for (int o = 0; o < ODIM; ++o) {
        float s0 = acc0[o], s1 = acc1[o];
        for (int off = 32; off > 0; off >>= 1) {
            s0 += __shfl_down(s0, off, 64);
            s1 += __shfl_down(s1, off, 64);
        }
        acc0[o] = s0; acc1[o] = s1;
    }

    __shared__ float red[4][2 * ODIM];
    int wave = tid >> 6;
    int lane = tid & 63;
    if (lane == 0) {
#pragma unroll
        for (int o = 0; o < ODIM; ++o) {
            red[wave][o] = acc0[o];
            red[wave][ODIM + o] = acc1[o];
        }
    }
    __syncthreads();
    if (tid < 2 * ODIM) {
        float tsum = red[0][tid] + red[1][tid] + red[2][tid] + red[3][tid];
        int bt = tid / ODIM;
        int o  = tid - bt * ODIM;
        out[(size_t)(b0 + bt) * ODIM + o] = tsum;
    }
}

extern "C" void kernel_launch(void* const* d_in, const int* in_sizes, int n_in,
                              void* d_out, int out_size, void* d_ws, size_t ws_size,
                              hipStream_t stream) {
    const float* x = (const float*)d_in[0];   // (512, 3, 64, 64)
    const float* G = (const float*)d_in[1];   // (512, 3844)
    const float* v = (const float*)d_in[2];   // (512, 27, 10)
    const float* w = (const float*)d_in[3];   // (512, 27, 10)
    float* out = (float*)d_out;               // (512, 10)

    // ws layout:
    //   S   fp32 [10][12288] =   491,520 B   (atomic-accumulated)
    //   Gt  bf16 [3904][512] = 3,997,696 B
    //   Pdt bf16 [272][512]  =   278,528 B
    char* wsb = (char*)d_ws;
    float*          S   = (float*)wsb;
    __hip_bfloat16* Gt  = (__hip_bfloat16*)(wsb + 491520);
    __hip_bfloat16* Pdt = (__hip_bfloat16*)(wsb + 491520 + 3997696);

    prep_kernel<<<1512, 256, 0, stream>>>(G, v, w, Gt, Pdt, S);

    tmfma_kernel<<<272, 256, 0, stream>>>(Pdt, Gt, S);

    out_gemm_kernel<<<BATCH / 2, 256, 0, stream>>>(x, S, out);
}